// Round 3
// baseline (1341.852 us; speedup 1.0000x reference)
//
#include <hip/hip_runtime.h>
#include <hip/hip_bf16.h>

#define T_TOKENS 8192
#define DM 1024
#define DF 4096
#define NE 8
#define NROWS 16384  // T_TOKENS * TOP_K

typedef __attribute__((ext_vector_type(8))) short bf16x8;
typedef __attribute__((ext_vector_type(4))) float f32x4;

__device__ inline unsigned short f2bf(float f) {
  unsigned int u = __builtin_bit_cast(unsigned int, f);
  u = (u + 0x7fffu + ((u >> 16) & 1u)) >> 16;  // round-to-nearest-even
  return (unsigned short)u;
}

// async global->LDS, 16 bytes per lane; LDS dest = wave-uniform base + lane*16
__device__ __forceinline__ void gload16(const unsigned short* g, unsigned short* l) {
  __builtin_amdgcn_global_load_lds(
      (const __attribute__((address_space(1))) unsigned int*)g,
      (__attribute__((address_space(3))) unsigned int*)l,
      16, 0, 0);
}

// ---------------- Router: one wave per token ----------------
__global__ void router_kernel(const float* __restrict__ x,
                              const float* __restrict__ Wr,
                              const float* __restrict__ br,
                              int* __restrict__ ctrl,   // [0..8) counts
                              int* __restrict__ tope,
                              float* __restrict__ topw) {
  const int wid = threadIdx.x >> 6;
  const int lane = threadIdx.x & 63;
  const int t = blockIdx.x * 4 + wid;
  const float* xr = x + (size_t)t * DM;
  float a[NE];
#pragma unroll
  for (int e = 0; e < NE; ++e) a[e] = 0.f;
#pragma unroll
  for (int it = 0; it < 4; ++it) {
    const int d0 = it * 256 + lane * 4;
    const float4 xv = *(const float4*)(xr + d0);
    const float xs[4] = {xv.x, xv.y, xv.z, xv.w};
#pragma unroll
    for (int j = 0; j < 4; ++j) {
      const float4 wa = *(const float4*)(Wr + (size_t)(d0 + j) * NE);
      const float4 wb = *(const float4*)(Wr + (size_t)(d0 + j) * NE + 4);
      a[0] += xs[j] * wa.x; a[1] += xs[j] * wa.y;
      a[2] += xs[j] * wa.z; a[3] += xs[j] * wa.w;
      a[4] += xs[j] * wb.x; a[5] += xs[j] * wb.y;
      a[6] += xs[j] * wb.z; a[7] += xs[j] * wb.w;
    }
  }
#pragma unroll
  for (int off = 32; off > 0; off >>= 1) {
#pragma unroll
    for (int e = 0; e < NE; ++e) a[e] += __shfl_xor(a[e], off);
  }
  if (lane == 0) {
    float lg[NE];
    float m = -1e30f;
#pragma unroll
    for (int e = 0; e < NE; ++e) { lg[e] = a[e] + br[e]; m = fmaxf(m, lg[e]); }
    float p[NE];
#pragma unroll
    for (int e = 0; e < NE; ++e) p[e] = expf(lg[e] - m);
    int i0 = 0;
#pragma unroll
    for (int e = 1; e < NE; ++e) if (p[e] > p[i0]) i0 = e;
    int i1 = (i0 == 0) ? 1 : 0;
#pragma unroll
    for (int e = 0; e < NE; ++e) if (e != i0 && p[e] > p[i1]) i1 = e;
    const float s = p[i0] + p[i1];
    tope[2 * t] = i0;
    tope[2 * t + 1] = i1;
    topw[2 * t] = p[i0] / s;
    topw[2 * t + 1] = p[i1] / s;
    atomicAdd(&ctrl[i0], 1);
    atomicAdd(&ctrl[i1], 1);
  }
}

// ---------------- Scan: offsets + cursors ----------------
__global__ void scan_kernel(int* __restrict__ ctrl) {
  if (threadIdx.x == 0 && blockIdx.x == 0) {
    int off = 0;
    for (int e = 0; e < NE; ++e) {
      ctrl[8 + e] = off;    // offsets
      ctrl[20 + e] = off;   // cursors
      off += ctrl[e];
    }
    ctrl[16] = off;
  }
}

// ---------------- Place: compact row lists ----------------
__global__ void place_kernel(const int* __restrict__ tope,
                             const float* __restrict__ topw,
                             int* __restrict__ ctrl,
                             int* __restrict__ rowlist,
                             float* __restrict__ roww) {
  const int t = blockIdx.x * blockDim.x + threadIdx.x;
#pragma unroll
  for (int k = 0; k < 2; ++k) {
    const int e = tope[2 * t + k];
    const int pos = atomicAdd(&ctrl[20 + e], 1);
    rowlist[pos] = t;
    roww[pos] = topw[2 * t + k];
  }
}

// ---------------- Convert x fp32 -> bf16 ----------------
__global__ void cvt_x_kernel(const float* __restrict__ x,
                             unsigned short* __restrict__ xb) {
  const size_t i = ((size_t)blockIdx.x * blockDim.x + threadIdx.x) * 4;
  const float4 v = *(const float4*)(x + i);
  ushort4 o;
  o.x = f2bf(v.x); o.y = f2bf(v.y); o.z = f2bf(v.z); o.w = f2bf(v.w);
  *(ushort4*)(xb + i) = o;
}

// ---------------- Transpose-convert: in [E][R][C] fp32 -> out [E][C][R] bf16 ----------------
__global__ void transpose_cvt_kernel(const float* __restrict__ in,
                                     unsigned short* __restrict__ outp,
                                     int R, int C) {
  __shared__ float tile[64][65];
  const int e = blockIdx.z;
  const int r0 = blockIdx.y * 64;
  const int c0 = blockIdx.x * 64;
  const float* src = in + ((size_t)e * R + r0) * C + c0;
#pragma unroll
  for (int i = 0; i < 16; ++i) {
    const int rr = (threadIdx.x >> 6) + i * 4;
    const int cc = threadIdx.x & 63;
    tile[rr][cc] = src[(size_t)rr * C + cc];
  }
  __syncthreads();
  unsigned short* dst = outp + ((size_t)e * C + c0) * R + r0;
#pragma unroll
  for (int i = 0; i < 8; ++i) {
    const int rr = (threadIdx.x >> 5) + i * 8;     // row of out tile (c index)
    const int cc = (threadIdx.x & 31) * 2;         // col of out tile (r index)
    const unsigned int lo = f2bf(tile[cc][rr]);
    const unsigned int hi = f2bf(tile[cc + 1][rr]);
    *(unsigned int*)(dst + (size_t)rr * R + cc) = lo | (hi << 16);
  }
}

// ---------------- GEMM1: h = gelu(x[rows] @ W1[e] + b1[e]) ----------------
// m97 structure + XOR-swizzled LDS chunks: physical chunk c of row r holds
// logical chunk c^(r&7); fragment reads use chunk (ks*4+q)^(l16&7).
__global__ __launch_bounds__(256, 4) void gemm1_kernel(
    const unsigned short* __restrict__ xb,   // [T][DM]
    const unsigned short* __restrict__ w1t,  // [E][DF][DM]
    const float* __restrict__ b1,            // [E][DF]
    const int* __restrict__ ctrl,
    const int* __restrict__ rowlist,
    unsigned short* __restrict__ h) {        // [NROWS][DF]
  const int e = blockIdx.z;
  const int count = ctrl[e];
  const int mt = blockIdx.y;
  if (mt * 128 >= count) return;
  const int off = ctrl[8 + e];
  const int n0 = blockIdx.x * 128;
  const int tid = threadIdx.x;
  const int wid = tid >> 6;
  const int lane = tid & 63;
  const int wm = (wid & 1) * 64;
  const int wn = (wid >> 1) * 64;
  const int q = lane >> 4;
  const int l16 = lane & 15;
  const int rl = lane >> 3;   // 0..7 (row within 8-row stage slab)
  const int ch = lane & 7;    // physical 16B chunk within 64-elt row
  const int gch = ch ^ rl;    // logical (global) chunk this lane stages

  __shared__ __attribute__((aligned(16))) unsigned short lA[128 * 64];
  __shared__ __attribute__((aligned(16))) unsigned short lB[128 * 64];

  const unsigned short* aBase[4];
  const unsigned short* bBase[4];
  unsigned short* lABase[4];
  unsigned short* lBBase[4];
#pragma unroll
  for (int i = 0; i < 4; ++i) {
    const int r = wid * 32 + i * 8 + rl;   // tile row 0..127
    int rr = mt * 128 + r;
    if (rr >= count) rr = count - 1;       // expert-local clamp
    const int tok = rowlist[off + rr];
    aBase[i] = xb + (size_t)tok * DM + gch * 8;
    bBase[i] = w1t + ((size_t)e * DF + n0 + r) * DM + gch * 8;
    lABase[i] = &lA[(wid * 32 + i * 8) * 64];  // wave-uniform
    lBBase[i] = &lB[(wid * 32 + i * 8) * 64];
  }

  // swizzled fragment chunk byte... element offsets for ks=0,1
  const int xv = l16 & 7;
  const int cks0 = ((0 * 4 + q) ^ xv) * 8;
  const int cks1 = ((1 * 4 + q) ^ xv) * 8;

  f32x4 acc[4][4];
  const f32x4 z = {0.f, 0.f, 0.f, 0.f};
#pragma unroll
  for (int im = 0; im < 4; ++im)
#pragma unroll
    for (int in = 0; in < 4; ++in) acc[im][in] = z;

  for (int k0 = 0; k0 < DM; k0 += 64) {
#pragma unroll
    for (int i = 0; i < 4; ++i) gload16(aBase[i] + k0, lABase[i]);
#pragma unroll
    for (int i = 0; i < 4; ++i) gload16(bBase[i] + k0, lBBase[i]);
    __syncthreads();
#pragma unroll
    for (int ks = 0; ks < 2; ++ks) {
      const int cks = ks ? cks1 : cks0;
      bf16x8 af[4], bfr[4];
#pragma unroll
      for (int im = 0; im < 4; ++im)
        af[im] = *(const bf16x8*)&lA[(wm + im * 16 + l16) * 64 + cks];
#pragma unroll
      for (int in = 0; in < 4; ++in)
        bfr[in] = *(const bf16x8*)&lB[(wn + in * 16 + l16) * 64 + cks];
#pragma unroll
      for (int im = 0; im < 4; ++im)
#pragma unroll
        for (int in = 0; in < 4; ++in)
          acc[im][in] = __builtin_amdgcn_mfma_f32_16x16x32_bf16(
              af[im], bfr[in], acc[im][in], 0, 0, 0);
    }
    __syncthreads();
  }

#pragma unroll
  for (int in = 0; in < 4; ++in) {
    const int col = n0 + wn + in * 16 + l16;
    const float bias = b1[(size_t)e * DF + col];
#pragma unroll
    for (int im = 0; im < 4; ++im) {
      const int rbase = mt * 128 + wm + im * 16 + q * 4;
#pragma unroll
      for (int r2 = 0; r2 < 4; ++r2) {
        const int r = rbase + r2;
        if (r < count) {
          const float v = acc[im][in][r2] + bias;
          const float g = 0.5f * v * (1.0f + erff(v * 0.70710678118f));
          h[((size_t)(off + r)) * DF + col] = f2bf(g);
        }
      }
    }
  }
}

// ---------------- GEMM2: out[tok] += w * (h[rows] @ W2[e] + b2[e]) ----------------
__global__ __launch_bounds__(256, 4) void gemm2_kernel(
    const unsigned short* __restrict__ h,    // [NROWS][DF]
    const unsigned short* __restrict__ w2t,  // [E][DM][DF]
    const float* __restrict__ b2,            // [E][DM]
    const int* __restrict__ ctrl,
    const int* __restrict__ rowlist,
    const float* __restrict__ roww,
    float* __restrict__ out) {               // [T][DM]
  const int e = blockIdx.z;
  const int count = ctrl[e];
  const int mt = blockIdx.y;
  if (mt * 128 >= count) return;
  const int off = ctrl[8 + e];
  const int n0 = blockIdx.x * 128;
  const int tid = threadIdx.x;
  const int wid = tid >> 6;
  const int lane = tid & 63;
  const int wm = (wid & 1) * 64;
  const int wn = (wid >> 1) * 64;
  const int q = lane >> 4;
  const int l16 = lane & 15;
  const int rl = lane >> 3;
  const int ch = lane & 7;
  const int gch = ch ^ rl;

  __shared__ __attribute__((aligned(16))) unsigned short lA[128 * 64];
  __shared__ __attribute__((aligned(16))) unsigned short lB[128 * 64];

  const unsigned short* aBase[4];
  const unsigned short* bBase[4];
  unsigned short* lABase[4];
  unsigned short* lBBase[4];
#pragma unroll
  for (int i = 0; i < 4; ++i) {
    const int r = wid * 32 + i * 8 + rl;
    int rr = mt * 128 + r;
    if (rr >= count) rr = count - 1;       // expert-local clamp (h written there)
    aBase[i] = h + (size_t)(off + rr) * DF + gch * 8;
    bBase[i] = w2t + ((size_t)e * DM + n0 + r) * DF + gch * 8;
    lABase[i] = &lA[(wid * 32 + i * 8) * 64];
    lBBase[i] = &lB[(wid * 32 + i * 8) * 64];
  }

  const int xv = l16 & 7;
  const int cks0 = ((0 * 4 + q) ^ xv) * 8;
  const int cks1 = ((1 * 4 + q) ^ xv) * 8;

  f32x4 acc[4][4];
  const f32x4 z = {0.f, 0.f, 0.f, 0.f};
#pragma unroll
  for (int im = 0; im < 4; ++im)
#pragma unroll
    for (int in = 0; in < 4; ++in) acc[im][in] = z;

  for (int k0 = 0; k0 < DF; k0 += 64) {
#pragma unroll
    for (int i = 0; i < 4; ++i) gload16(aBase[i] + k0, lABase[i]);
#pragma unroll
    for (int i = 0; i < 4; ++i) gload16(bBase[i] + k0, lBBase[i]);
    __syncthreads();
#pragma unroll
    for (int ks = 0; ks < 2; ++ks) {
      const int cks = ks ? cks1 : cks0;
      bf16x8 af[4], bfr[4];
#pragma unroll
      for (int im = 0; im < 4; ++im)
        af[im] = *(const bf16x8*)&lA[(wm + im * 16 + l16) * 64 + cks];
#pragma unroll
      for (int in = 0; in < 4; ++in)
        bfr[in] = *(const bf16x8*)&lB[(wn + in * 16 + l16) * 64 + cks];
#pragma unroll
      for (int im = 0; im < 4; ++im)
#pragma unroll
        for (int in = 0; in < 4; ++in)
          acc[im][in] = __builtin_amdgcn_mfma_f32_16x16x32_bf16(
              af[im], bfr[in], acc[im][in], 0, 0, 0);
    }
    __syncthreads();
  }

#pragma unroll
  for (int in = 0; in < 4; ++in) {
    const int col = n0 + wn + in * 16 + l16;
    const float bias = b2[(size_t)e * DM + col];
#pragma unroll
    for (int im = 0; im < 4; ++im) {
      const int rbase = mt * 128 + wm + im * 16 + q * 4;
#pragma unroll
      for (int r2 = 0; r2 < 4; ++r2) {
        const int r = rbase + r2;
        if (r < count) {
          const int pos = off + r;
          const int tok = rowlist[pos];
          const float w = roww[pos];
          atomicAdd(&out[(size_t)tok * DM + col], (acc[im][in][r2] + bias) * w);
        }
      }
    }
  }
}

extern "C" void kernel_launch(void* const* d_in, const int* in_sizes, int n_in,
                              void* d_out, int out_size, void* d_ws, size_t ws_size,
                              hipStream_t stream) {
  const float* x  = (const float*)d_in[0];
  const float* Wr = (const float*)d_in[1];
  const float* br = (const float*)d_in[2];
  const float* W1 = (const float*)d_in[3];
  const float* b1 = (const float*)d_in[4];
  const float* W2 = (const float*)d_in[5];
  const float* b2 = (const float*)d_in[6];
  float* out = (float*)d_out;

  char* p = (char*)d_ws;
  auto alloc = [&](size_t bytes) -> char* {
    char* r = p;
    p += (bytes + 255) & ~(size_t)255;
    return r;
  };
  int* ctrl = (int*)alloc(1024);
  int* tope = (int*)alloc((size_t)2 * T_TOKENS * 4);
  float* topw = (float*)alloc((size_t)2 * T_TOKENS * 4);
  int* rowlist = (int*)alloc((size_t)NROWS * 4);
  float* roww = (float*)alloc((size_t)NROWS * 4);
  unsigned short* xb  = (unsigned short*)alloc((size_t)T_TOKENS * DM * 2);
  unsigned short* w1t = (unsigned short*)alloc((size_t)NE * DF * DM * 2);
  unsigned short* w2t = (unsigned short*)alloc((size_t)NE * DM * DF * 2);
  unsigned short* h   = (unsigned short*)alloc((size_t)NROWS * DF * 2);
  if ((size_t)(p - (char*)d_ws) > ws_size) return;  // insufficient workspace

  hipMemsetAsync(ctrl, 0, 1024, stream);
  hipMemsetAsync(d_out, 0, sizeof(float) * (size_t)out_size, stream);

  router_kernel<<<T_TOKENS / 4, 256, 0, stream>>>(x, Wr, br, ctrl, tope, topw);
  scan_kernel<<<1, 64, 0, stream>>>(ctrl);
  place_kernel<<<T_TOKENS / 256, 256, 0, stream>>>(tope, topw, ctrl, rowlist, roww);
  cvt_x_kernel<<<(T_TOKENS * DM / 4) / 256, 256, 0, stream>>>(x, xb);
  transpose_cvt_kernel<<<dim3(DF / 64, DM / 64, NE), 256, 0, stream>>>(W1, w1t, DM, DF);
  transpose_cvt_kernel<<<dim3(DM / 64, DF / 64, NE), 256, 0, stream>>>(W2, w2t, DF, DM);
  gemm1_kernel<<<dim3(DF / 128, 64, NE), 256, 0, stream>>>(xb, w1t, b1, ctrl, rowlist, h);
  gemm2_kernel<<<dim3(DM / 128, 64, NE), 256, 0, stream>>>(h, w2t, b2, ctrl, rowlist, roww, out);
}

// Round 4
// 1123.017 us; speedup vs baseline: 1.1949x; 1.1949x over previous
//
#include <hip/hip_runtime.h>
#include <hip/hip_bf16.h>

#define T_TOKENS 8192
#define DM 1024
#define DF 4096
#define NE 8
#define NROWS 16384  // T_TOKENS * TOP_K

typedef __attribute__((ext_vector_type(8))) short bf16x8;
typedef __attribute__((ext_vector_type(4))) float f32x4;

__device__ inline unsigned short f2bf(float f) {
  unsigned int u = __builtin_bit_cast(unsigned int, f);
  u = (u + 0x7fffu + ((u >> 16) & 1u)) >> 16;  // round-to-nearest-even
  return (unsigned short)u;
}

__device__ inline float bf2f(unsigned short s) {
  unsigned int u = ((unsigned int)s) << 16;
  return __builtin_bit_cast(float, u);
}

// async global->LDS, 16 bytes per lane; LDS dest = wave-uniform base + lane*16
__device__ __forceinline__ void gload16(const unsigned short* g, unsigned short* l) {
  __builtin_amdgcn_global_load_lds(
      (const __attribute__((address_space(1))) unsigned int*)g,
      (__attribute__((address_space(3))) unsigned int*)l,
      16, 0, 0);
}

// ---------------- Router: one wave per token; also emits xb (bf16 x) ----------------
__global__ void router_kernel(const float* __restrict__ x,
                              const float* __restrict__ Wr,
                              const float* __restrict__ br,
                              int* __restrict__ ctrl,   // [0..8) counts
                              int* __restrict__ tope,
                              float* __restrict__ topw,
                              unsigned short* __restrict__ xb) {
  const int wid = threadIdx.x >> 6;
  const int lane = threadIdx.x & 63;
  const int t = blockIdx.x * 4 + wid;
  const float* xr = x + (size_t)t * DM;
  unsigned short* xbr = xb + (size_t)t * DM;
  float a[NE];
#pragma unroll
  for (int e = 0; e < NE; ++e) a[e] = 0.f;
#pragma unroll
  for (int it = 0; it < 4; ++it) {
    const int d0 = it * 256 + lane * 4;
    const float4 xv = *(const float4*)(xr + d0);
    ushort4 o;
    o.x = f2bf(xv.x); o.y = f2bf(xv.y); o.z = f2bf(xv.z); o.w = f2bf(xv.w);
    *(ushort4*)(xbr + d0) = o;  // fused x -> bf16 conversion
    const float xs[4] = {xv.x, xv.y, xv.z, xv.w};
#pragma unroll
    for (int j = 0; j < 4; ++j) {
      const float4 wa = *(const float4*)(Wr + (size_t)(d0 + j) * NE);
      const float4 wb = *(const float4*)(Wr + (size_t)(d0 + j) * NE + 4);
      a[0] += xs[j] * wa.x; a[1] += xs[j] * wa.y;
      a[2] += xs[j] * wa.z; a[3] += xs[j] * wa.w;
      a[4] += xs[j] * wb.x; a[5] += xs[j] * wb.y;
      a[6] += xs[j] * wb.z; a[7] += xs[j] * wb.w;
    }
  }
#pragma unroll
  for (int off = 32; off > 0; off >>= 1) {
#pragma unroll
    for (int e = 0; e < NE; ++e) a[e] += __shfl_xor(a[e], off);
  }
  if (lane == 0) {
    float lg[NE];
    float m = -1e30f;
#pragma unroll
    for (int e = 0; e < NE; ++e) { lg[e] = a[e] + br[e]; m = fmaxf(m, lg[e]); }
    float p[NE];
#pragma unroll
    for (int e = 0; e < NE; ++e) p[e] = expf(lg[e] - m);
    int i0 = 0;
#pragma unroll
    for (int e = 1; e < NE; ++e) if (p[e] > p[i0]) i0 = e;
    int i1 = (i0 == 0) ? 1 : 0;
#pragma unroll
    for (int e = 0; e < NE; ++e) if (e != i0 && p[e] > p[i1]) i1 = e;
    const float s = p[i0] + p[i1];
    tope[2 * t] = i0;
    tope[2 * t + 1] = i1;
    topw[2 * t] = p[i0] / s;
    topw[2 * t + 1] = p[i1] / s;
    atomicAdd(&ctrl[i0], 1);
    atomicAdd(&ctrl[i1], 1);
  }
}

// ---------------- Scan: offsets + cursors ----------------
__global__ void scan_kernel(int* __restrict__ ctrl) {
  if (threadIdx.x == 0 && blockIdx.x == 0) {
    int off = 0;
    for (int e = 0; e < NE; ++e) {
      ctrl[8 + e] = off;    // offsets
      ctrl[20 + e] = off;   // cursors
      off += ctrl[e];
    }
    ctrl[16] = off;
  }
}

// ---------------- Place: compact row lists + inverse map ----------------
__global__ void place_kernel(const int* __restrict__ tope,
                             const float* __restrict__ topw,
                             int* __restrict__ ctrl,
                             int* __restrict__ rowlist,
                             float* __restrict__ roww,
                             int* __restrict__ posmap) {
  const int t = blockIdx.x * blockDim.x + threadIdx.x;
#pragma unroll
  for (int k = 0; k < 2; ++k) {
    const int e = tope[2 * t + k];
    const int pos = atomicAdd(&ctrl[20 + e], 1);
    rowlist[pos] = t;
    roww[pos] = topw[2 * t + k];
    posmap[2 * t + k] = pos;
  }
}

// ---------------- Transpose-convert: in [E][R][C] fp32 -> out [E][C][R] bf16 ----------------
__global__ void transpose_cvt_kernel(const float* __restrict__ in,
                                     unsigned short* __restrict__ outp,
                                     int R, int C) {
  __shared__ float tile[64][65];
  const int e = blockIdx.z;
  const int r0 = blockIdx.y * 64;
  const int c0 = blockIdx.x * 64;
  const float* src = in + ((size_t)e * R + r0) * C + c0;
#pragma unroll
  for (int i = 0; i < 16; ++i) {
    const int rr = (threadIdx.x >> 6) + i * 4;
    const int cc = threadIdx.x & 63;
    tile[rr][cc] = src[(size_t)rr * C + cc];
  }
  __syncthreads();
  unsigned short* dst = outp + ((size_t)e * C + c0) * R + r0;
#pragma unroll
  for (int i = 0; i < 8; ++i) {
    const int rr = (threadIdx.x >> 5) + i * 8;     // row of out tile (c index)
    const int cc = (threadIdx.x & 31) * 2;         // col of out tile (r index)
    const unsigned int lo = f2bf(tile[cc][rr]);
    const unsigned int hi = f2bf(tile[cc + 1][rr]);
    *(unsigned int*)(dst + (size_t)rr * R + cc) = lo | (hi << 16);
  }
}

// ---------------- GEMM1: h = gelu(x[rows] @ W1[e] + b1[e]) ----------------
// m97 structure: BK=64, unpadded LDS [128][64] bf16, global_load_lds dwordx4
__global__ __launch_bounds__(256, 2) void gemm1_kernel(
    const unsigned short* __restrict__ xb,   // [T][DM]
    const unsigned short* __restrict__ w1t,  // [E][DF][DM]
    const float* __restrict__ b1,            // [E][DF]
    const int* __restrict__ ctrl,
    const int* __restrict__ rowlist,
    unsigned short* __restrict__ h) {        // [NROWS][DF]
  const int e = blockIdx.z;
  const int count = ctrl[e];
  const int mt = blockIdx.y;
  if (mt * 128 >= count) return;
  const int off = ctrl[8 + e];
  const int n0 = blockIdx.x * 128;
  const int tid = threadIdx.x;
  const int wid = tid >> 6;
  const int lane = tid & 63;
  const int wm = (wid & 1) * 64;
  const int wn = (wid >> 1) * 64;
  const int q = lane >> 4;
  const int l16 = lane & 15;
  const int rl = lane >> 3;   // 0..7 (row within 8-row stage slab)
  const int ch = lane & 7;    // 16B chunk within 64-elt row

  __shared__ __attribute__((aligned(16))) unsigned short lA[128 * 64];
  __shared__ __attribute__((aligned(16))) unsigned short lB[128 * 64];

  const unsigned short* aBase[4];
  const unsigned short* bBase[4];
  unsigned short* lABase[4];
  unsigned short* lBBase[4];
#pragma unroll
  for (int i = 0; i < 4; ++i) {
    const int r = wid * 32 + i * 8 + rl;   // tile row 0..127
    int rr = mt * 128 + r;
    if (rr >= count) rr = count - 1;       // expert-local clamp
    const int tok = rowlist[off + rr];
    aBase[i] = xb + (size_t)tok * DM + ch * 8;
    bBase[i] = w1t + ((size_t)e * DF + n0 + r) * DM + ch * 8;
    lABase[i] = &lA[(wid * 32 + i * 8) * 64];  // wave-uniform
    lBBase[i] = &lB[(wid * 32 + i * 8) * 64];
  }

  f32x4 acc[4][4];
  const f32x4 z = {0.f, 0.f, 0.f, 0.f};
#pragma unroll
  for (int im = 0; im < 4; ++im)
#pragma unroll
    for (int in = 0; in < 4; ++in) acc[im][in] = z;

  for (int k0 = 0; k0 < DM; k0 += 64) {
#pragma unroll
    for (int i = 0; i < 4; ++i) gload16(aBase[i] + k0, lABase[i]);
#pragma unroll
    for (int i = 0; i < 4; ++i) gload16(bBase[i] + k0, lBBase[i]);
    __syncthreads();
#pragma unroll
    for (int ks = 0; ks < 2; ++ks) {
      bf16x8 af[4], bfr[4];
#pragma unroll
      for (int im = 0; im < 4; ++im)
        af[im] = *(const bf16x8*)&lA[(wm + im * 16 + l16) * 64 + ks * 32 + q * 8];
#pragma unroll
      for (int in = 0; in < 4; ++in)
        bfr[in] = *(const bf16x8*)&lB[(wn + in * 16 + l16) * 64 + ks * 32 + q * 8];
#pragma unroll
      for (int im = 0; im < 4; ++im)
#pragma unroll
        for (int in = 0; in < 4; ++in)
          acc[im][in] = __builtin_amdgcn_mfma_f32_16x16x32_bf16(
              af[im], bfr[in], acc[im][in], 0, 0, 0);
    }
    __syncthreads();
  }

#pragma unroll
  for (int in = 0; in < 4; ++in) {
    const int col = n0 + wn + in * 16 + l16;
    const float bias = b1[(size_t)e * DF + col];
#pragma unroll
    for (int im = 0; im < 4; ++im) {
      const int rbase = mt * 128 + wm + im * 16 + q * 4;
#pragma unroll
      for (int r2 = 0; r2 < 4; ++r2) {
        const int r = rbase + r2;
        if (r < count) {
          const float v = acc[im][in][r2] + bias;
          const float g = 0.5f * v * (1.0f + erff(v * 0.70710678118f));
          h[((size_t)(off + r)) * DF + col] = f2bf(g);
        }
      }
    }
  }
}

// ---------------- GEMM2: y[row] = h[row] @ W2[e] + b2[e]  (plain stores, no atomics) ----------------
__global__ __launch_bounds__(256, 2) void gemm2_kernel(
    const unsigned short* __restrict__ h,    // [NROWS][DF]
    const unsigned short* __restrict__ w2t,  // [E][DM][DF]
    const float* __restrict__ b2,            // [E][DM]
    const int* __restrict__ ctrl,
    unsigned short* __restrict__ y) {        // [NROWS][DM] bf16, bias folded
  const int e = blockIdx.z;
  const int count = ctrl[e];
  const int mt = blockIdx.y;
  if (mt * 128 >= count) return;
  const int off = ctrl[8 + e];
  const int n0 = blockIdx.x * 128;
  const int tid = threadIdx.x;
  const int wid = tid >> 6;
  const int lane = tid & 63;
  const int wm = (wid & 1) * 64;
  const int wn = (wid >> 1) * 64;
  const int q = lane >> 4;
  const int l16 = lane & 15;
  const int rl = lane >> 3;
  const int ch = lane & 7;

  __shared__ __attribute__((aligned(16))) unsigned short lA[128 * 64];
  __shared__ __attribute__((aligned(16))) unsigned short lB[128 * 64];

  const unsigned short* aBase[4];
  const unsigned short* bBase[4];
  unsigned short* lABase[4];
  unsigned short* lBBase[4];
#pragma unroll
  for (int i = 0; i < 4; ++i) {
    const int r = wid * 32 + i * 8 + rl;
    int rr = mt * 128 + r;
    if (rr >= count) rr = count - 1;       // expert-local clamp (h written there)
    aBase[i] = h + (size_t)(off + rr) * DF + ch * 8;
    bBase[i] = w2t + ((size_t)e * DM + n0 + r) * DF + ch * 8;
    lABase[i] = &lA[(wid * 32 + i * 8) * 64];
    lBBase[i] = &lB[(wid * 32 + i * 8) * 64];
  }

  f32x4 acc[4][4];
  const f32x4 z = {0.f, 0.f, 0.f, 0.f};
#pragma unroll
  for (int im = 0; im < 4; ++im)
#pragma unroll
    for (int in = 0; in < 4; ++in) acc[im][in] = z;

  for (int k0 = 0; k0 < DF; k0 += 64) {
#pragma unroll
    for (int i = 0; i < 4; ++i) gload16(aBase[i] + k0, lABase[i]);
#pragma unroll
    for (int i = 0; i < 4; ++i) gload16(bBase[i] + k0, lBBase[i]);
    __syncthreads();
#pragma unroll
    for (int ks = 0; ks < 2; ++ks) {
      bf16x8 af[4], bfr[4];
#pragma unroll
      for (int im = 0; im < 4; ++im)
        af[im] = *(const bf16x8*)&lA[(wm + im * 16 + l16) * 64 + ks * 32 + q * 8];
#pragma unroll
      for (int in = 0; in < 4; ++in)
        bfr[in] = *(const bf16x8*)&lB[(wn + in * 16 + l16) * 64 + ks * 32 + q * 8];
#pragma unroll
      for (int im = 0; im < 4; ++im)
#pragma unroll
        for (int in = 0; in < 4; ++in)
          acc[im][in] = __builtin_amdgcn_mfma_f32_16x16x32_bf16(
              af[im], bfr[in], acc[im][in], 0, 0, 0);
    }
    __syncthreads();
  }

#pragma unroll
  for (int in = 0; in < 4; ++in) {
    const int col = n0 + wn + in * 16 + l16;
    const float bias = b2[(size_t)e * DM + col];
#pragma unroll
    for (int im = 0; im < 4; ++im) {
      const int rbase = mt * 128 + wm + im * 16 + q * 4;
#pragma unroll
      for (int r2 = 0; r2 < 4; ++r2) {
        const int r = rbase + r2;
        if (r < count) {
          y[(size_t)(off + r) * DM + col] = f2bf(acc[im][in][r2] + bias);
        }
      }
    }
  }
}

// ---------------- Combine: out[t] = w0*y[p0] + w1*y[p1] ----------------
__global__ void combine_kernel(const unsigned short* __restrict__ y,
                               const int* __restrict__ posmap,
                               const float* __restrict__ topw,
                               float* __restrict__ out) {
  const int t = blockIdx.x;
  const int c = threadIdx.x * 4;
  const int p0 = posmap[2 * t];
  const int p1 = posmap[2 * t + 1];
  const float w0 = topw[2 * t];
  const float w1 = topw[2 * t + 1];
  const ushort4 a = *(const ushort4*)(y + (size_t)p0 * DM + c);
  const ushort4 b = *(const ushort4*)(y + (size_t)p1 * DM + c);
  float4 o;
  o.x = w0 * bf2f(a.x) + w1 * bf2f(b.x);
  o.y = w0 * bf2f(a.y) + w1 * bf2f(b.y);
  o.z = w0 * bf2f(a.z) + w1 * bf2f(b.z);
  o.w = w0 * bf2f(a.w) + w1 * bf2f(b.w);
  *(float4*)(out + (size_t)t * DM + c) = o;
}

extern "C" void kernel_launch(void* const* d_in, const int* in_sizes, int n_in,
                              void* d_out, int out_size, void* d_ws, size_t ws_size,
                              hipStream_t stream) {
  const float* x  = (const float*)d_in[0];
  const float* Wr = (const float*)d_in[1];
  const float* br = (const float*)d_in[2];
  const float* W1 = (const float*)d_in[3];
  const float* b1 = (const float*)d_in[4];
  const float* W2 = (const float*)d_in[5];
  const float* b2 = (const float*)d_in[6];
  float* out = (float*)d_out;

  char* p = (char*)d_ws;
  auto alloc = [&](size_t bytes) -> char* {
    char* r = p;
    p += (bytes + 255) & ~(size_t)255;
    return r;
  };
  int* ctrl = (int*)alloc(1024);
  int* tope = (int*)alloc((size_t)2 * T_TOKENS * 4);
  float* topw = (float*)alloc((size_t)2 * T_TOKENS * 4);
  int* rowlist = (int*)alloc((size_t)NROWS * 4);
  float* roww = (float*)alloc((size_t)NROWS * 4);
  int* posmap = (int*)alloc((size_t)NROWS * 4);
  unsigned short* xb  = (unsigned short*)alloc((size_t)T_TOKENS * DM * 2);
  unsigned short* w1t = (unsigned short*)alloc((size_t)NE * DF * DM * 2);
  unsigned short* w2t = (unsigned short*)alloc((size_t)NE * DM * DF * 2);
  unsigned short* h   = (unsigned short*)alloc((size_t)NROWS * DF * 2);
  if ((size_t)(p - (char*)d_ws) > ws_size) return;  // insufficient workspace

  // y_rows aliases w1t: w1t is only read by gemm1, which completes before
  // gemm2 writes y (same stream). 33.5 MB <= 67 MB region.
  unsigned short* y = w1t;

  hipMemsetAsync(ctrl, 0, 1024, stream);

  router_kernel<<<T_TOKENS / 4, 256, 0, stream>>>(x, Wr, br, ctrl, tope, topw, xb);
  scan_kernel<<<1, 64, 0, stream>>>(ctrl);
  place_kernel<<<T_TOKENS / 256, 256, 0, stream>>>(tope, topw, ctrl, rowlist, roww, posmap);
  transpose_cvt_kernel<<<dim3(DF / 64, DM / 64, NE), 256, 0, stream>>>(W1, w1t, DM, DF);
  transpose_cvt_kernel<<<dim3(DM / 64, DF / 64, NE), 256, 0, stream>>>(W2, w2t, DF, DM);
  gemm1_kernel<<<dim3(DF / 128, 64, NE), 256, 0, stream>>>(xb, w1t, b1, ctrl, rowlist, h);
  gemm2_kernel<<<dim3(DM / 128, 64, NE), 256, 0, stream>>>(h, w2t, b2, ctrl, y);
  combine_kernel<<<T_TOKENS, 256, 0, stream>>>(y, posmap, topw, out);
}